// Round 23
// baseline (175.127 us; speedup 1.0000x reference)
//
#include <hip/hip_runtime.h>
#include <hip/hip_bf16.h>
#include <stdint.h>

// MultiheadSelfAttention B=4 S=2048 D=1024 H=16 dh=64, causal, f32 in/out.
// R23: out-projection re-tiled to the R22-proven 256x128 / 512-thread
//      structure (grid 32x8 = 256 blocks = 1/CU single round). gemm_qkv,
//      attn (R16), casts unchanged.

#define S_LEN 2048
#define DM 1024
#define NH 16
#define NB 4
#define DH 64
#define BS (NB * S_LEN)   // 8192 rows

#if __has_builtin(__builtin_amdgcn_exp2f)
#define EXP2(x) __builtin_amdgcn_exp2f(x)
#else
#define EXP2(x) __expf((x) * 0.6931471805599453f)
#endif

typedef __attribute__((ext_vector_type(4))) float f32x4;
typedef __attribute__((ext_vector_type(16))) float f32x16;
typedef __attribute__((ext_vector_type(8))) short bf16x8;
typedef __attribute__((ext_vector_type(4))) short s16x4;

static __device__ __forceinline__ float bf2f(short u) {
    union { float f; uint32_t i; } c; c.i = ((uint32_t)(uint16_t)u) << 16; return c.f;
}
static __device__ __forceinline__ short f2bf(float f) {
    union { float f; uint32_t i; } c; c.f = f;
    uint32_t r = (c.i + 0x7FFFu + ((c.i >> 16) & 1u)) >> 16;
    return (short)r;
}

// ---------------- casts ----------------
__global__ void cast_kernel(const float* __restrict__ in, short* __restrict__ out, int n4) {
    int i = blockIdx.x * blockDim.x + threadIdx.x;
    if (i >= n4) return;
    f32x4 v = *(const f32x4*)(in + (size_t)i * 4);
    s16x4 o;
    o[0] = f2bf(v[0]); o[1] = f2bf(v[1]); o[2] = f2bf(v[2]); o[3] = f2bf(v[3]);
    *(s16x4*)(out + (size_t)i * 4) = o;
}

__global__ void cast4_kernel(const float* __restrict__ a, const float* __restrict__ b,
                             const float* __restrict__ c, const float* __restrict__ d,
                             short* __restrict__ out, int n4per) {
    int z = blockIdx.y;
    const float* in = z == 0 ? a : z == 1 ? b : z == 2 ? c : d;
    int i = blockIdx.x * blockDim.x + threadIdx.x;
    if (i >= n4per) return;
    f32x4 v = *(const f32x4*)(in + (size_t)i * 4);
    s16x4 o;
    o[0] = f2bf(v[0]); o[1] = f2bf(v[1]); o[2] = f2bf(v[2]); o[3] = f2bf(v[3]);
    *(s16x4*)(out + (size_t)z * n4per * 4 + (size_t)i * 4) = o;
}

// ---------------- fused QKV GEMM, 256x128 tile, 512 threads (R22) ------------
__global__ __launch_bounds__(512) void gemm_qkv(const short* __restrict__ A,
                                                const short* __restrict__ Bm,
                                                short* __restrict__ Outb) {
    __shared__ __align__(16) short lA[2][256 * 32];   // 32KB
    __shared__ __align__(16) short lB[2][128 * 32];   // 16KB
    const int Kd = DM;
    const int tid = threadIdx.x;
    const int lane = tid & 63;
    const int wave = tid >> 6;          // 0..7
    const int wave_m = wave >> 1;       // 0..3
    const int wave_n = wave & 1;        // 0..1
    const int mb = blockIdx.x;
    const int nb = blockIdx.y;
    const int c16 = lane & 15;
    const int g = lane >> 4;

    auto stage = [&](int buf, int kb) {
        #pragma unroll
        for (int i = 0; i < 2; i++) {
            int row = i * 128 + wave * 16 + (lane >> 2);
            int col = (lane & 3) * 8;
            const short* srcA = A + (size_t)(mb * 256 + row) * Kd + kb * 32 + col;
            __builtin_amdgcn_global_load_lds(
                (const __attribute__((address_space(1))) void*)srcA,
                (__attribute__((address_space(3))) void*)(&lA[buf][i * 4096 + wave * 512]),
                16, 0, 0);
        }
        {
            int row = wave * 16 + (lane >> 2);
            int col = (lane & 3) * 8;
            const short* srcB = Bm + (size_t)(nb * 128 + row) * Kd + kb * 32 + col;
            __builtin_amdgcn_global_load_lds(
                (const __attribute__((address_space(1))) void*)srcB,
                (__attribute__((address_space(3))) void*)(&lB[buf][wave * 512]),
                16, 0, 0);
        }
    };

    f32x4 acc[4][4];
    f32x4 zero = {0.f, 0.f, 0.f, 0.f};
    for (int i = 0; i < 4; i++)
        for (int j = 0; j < 4; j++) acc[i][j] = zero;

    const int nk = Kd >> 5;
    stage(0, 0);
    __syncthreads();
    for (int t = 0; t < nk; t++) {
        int cur = t & 1;
        if (t + 1 < nk) stage(cur ^ 1, t + 1);
        bf16x8 af[4], bfr[4];
        for (int i = 0; i < 4; i++) {
            af[i]  = *(const bf16x8*)&lA[cur][(wave_m * 64 + i * 16 + c16) * 32 + g * 8];
            bfr[i] = *(const bf16x8*)&lB[cur][(wave_n * 64 + i * 16 + c16) * 32 + g * 8];
        }
        for (int mi = 0; mi < 4; mi++)
            for (int ni = 0; ni < 4; ni++)
                acc[mi][ni] = __builtin_amdgcn_mfma_f32_16x16x32_bf16(af[mi], bfr[ni], acc[mi][ni], 0, 0, 0);
        __syncthreads();
    }

    const int z = (nb * 128) >> 10;
    short* Cout = Outb + (size_t)z * BS * DM;
    for (int mi = 0; mi < 4; mi++) {
        int row0 = mb * 256 + wave_m * 64 + mi * 16 + g * 4;
        if (z < 2) {
            for (int ni = 0; ni < 4; ni++) {
                int col = (nb * 128 + wave_n * 64 + ni * 16 + c16) & 1023;
                f32x4 a = acc[mi][ni];
                for (int r = 0; r < 4; r++)
                    Cout[(size_t)(row0 + r) * DM + col] = f2bf(a[r]);
            }
        } else {
            int bb = row0 >> 11, s0 = row0 & 2047;
            int kb = s0 >> 5, kl0 = s0 & 31;
            int pos0 = kl0 ^ ((((kl0 >> 2) ^ (kl0 >> 3)) & 1) ? 12 : 0);
            for (int ni = 0; ni < 4; ni++) {
                int col = (nb * 128 + wave_n * 64 + ni * 16 + c16) & 1023;
                int h = col >> 6, d = col & 63;
                f32x4 a = acc[mi][ni];
                s16x4 v4;
                v4[0] = f2bf(a[0]); v4[1] = f2bf(a[1]);
                v4[2] = f2bf(a[2]); v4[3] = f2bf(a[3]);
                *(s16x4*)(Cout + ((((size_t)(bb * NH + h) * 64 + kb) * 64 + d) * 32 + pos0)) = v4;
            }
        }
    }
}

// ---------------- output GEMM, 256x128 tile, 512 threads, f32 out ------------
__global__ __launch_bounds__(512) void gemm_out(const short* __restrict__ A,
                                                const short* __restrict__ Bm,
                                                float* __restrict__ Cout) {
    __shared__ __align__(16) short lA[2][256 * 32];   // 32KB
    __shared__ __align__(16) short lB[2][128 * 32];   // 16KB
    const int Kd = DM;
    const int tid = threadIdx.x;
    const int lane = tid & 63;
    const int wave = tid >> 6;
    const int wave_m = wave >> 1;
    const int wave_n = wave & 1;
    const int mb = blockIdx.x;
    const int nb = blockIdx.y;
    const int c16 = lane & 15;
    const int g = lane >> 4;

    auto stage = [&](int buf, int kb) {
        #pragma unroll
        for (int i = 0; i < 2; i++) {
            int row = i * 128 + wave * 16 + (lane >> 2);
            int col = (lane & 3) * 8;
            const short* srcA = A + (size_t)(mb * 256 + row) * Kd + kb * 32 + col;
            __builtin_amdgcn_global_load_lds(
                (const __attribute__((address_space(1))) void*)srcA,
                (__attribute__((address_space(3))) void*)(&lA[buf][i * 4096 + wave * 512]),
                16, 0, 0);
        }
        {
            int row = wave * 16 + (lane >> 2);
            int col = (lane & 3) * 8;
            const short* srcB = Bm + (size_t)(nb * 128 + row) * Kd + kb * 32 + col;
            __builtin_amdgcn_global_load_lds(
                (const __attribute__((address_space(1))) void*)srcB,
                (__attribute__((address_space(3))) void*)(&lB[buf][wave * 512]),
                16, 0, 0);
        }
    };

    f32x4 acc[4][4];
    f32x4 zero = {0.f, 0.f, 0.f, 0.f};
    for (int i = 0; i < 4; i++)
        for (int j = 0; j < 4; j++) acc[i][j] = zero;

    const int nk = Kd >> 5;
    stage(0, 0);
    __syncthreads();
    for (int t = 0; t < nk; t++) {
        int cur = t & 1;
        if (t + 1 < nk) stage(cur ^ 1, t + 1);
        bf16x8 af[4], bfr[4];
        for (int i = 0; i < 4; i++) {
            af[i]  = *(const bf16x8*)&lA[cur][(wave_m * 64 + i * 16 + c16) * 32 + g * 8];
            bfr[i] = *(const bf16x8*)&lB[cur][(wave_n * 64 + i * 16 + c16) * 32 + g * 8];
        }
        for (int mi = 0; mi < 4; mi++)
            for (int ni = 0; ni < 4; ni++)
                acc[mi][ni] = __builtin_amdgcn_mfma_f32_16x16x32_bf16(af[mi], bfr[ni], acc[mi][ni], 0, 0, 0);
        __syncthreads();
    }

    for (int mi = 0; mi < 4; mi++) {
        int row0 = mb * 256 + wave_m * 64 + mi * 16 + g * 4;
        for (int ni = 0; ni < 4; ni++) {
            int col = nb * 128 + wave_n * 64 + ni * 16 + c16;
            f32x4 a = acc[mi][ni];
            for (int r = 0; r < 4; r++)
                Cout[(size_t)(row0 + r) * DM + col] = a[r];
        }
    }
}

// ---------------- flash attention (R16 exact): K LDS-staged, V direct ------------
__global__ __launch_bounds__(256, 4) void attn_stg_kernel(const short* __restrict__ Q,
                                                          const short* __restrict__ K,
                                                          const short* __restrict__ Vt,
                                                          short* __restrict__ Oo) {
    __shared__ __align__(16) char stg[4][4608];   // per-wave: K 4KB | partial/lL overlay
    const int lane = threadIdx.x & 63;
    const int wave = threadIdx.x >> 6;
    const int j = blockIdx.x >> 6;        // 0..31
    const int bh = blockIdx.x & 63;       // XCD = bh%8 (round-robin)
    const int b = bh >> 4, h = bh & 15;
    const int l31 = lane & 31;
    const int hi = lane >> 5;
    const bool three = (j <= 20);

    auto lLp = [&](int w) { return (float*)(stg[w] + 4352); };

    const int qtA = 63 - j, qtB = j;
    const int nkA = qtA + 1, nkB = qtB + 1;
    int qt, t0, t1;
    if (three) {
        if (wave < 3) { qt = qtA; t0 = (nkA * wave) / 3; t1 = (nkA * (wave + 1)) / 3; }
        else          { qt = qtB; t0 = 0; t1 = nkB; }
    } else {
        int half = wave & 1;
        if (wave < 2) { int hh = (nkA + 1) >> 1; qt = qtA; t0 = half ? hh : 0; t1 = half ? nkA : hh; }
        else          { int hh = (nkB + 1) >> 1; qt = qtB; t0 = half ? hh : 0; t1 = half ? nkB : hh; }
    }
    const int q0 = qt * 32;
    const int qrow = q0 + l31;

    const short* Qb = Q + (size_t)b * S_LEN * DM + h * DH;
    const short* Kb = K + (size_t)b * S_LEN * DM + h * DH;
    const short* Vb = Vt + (size_t)bh * S_LEN * DH;
    const float QSCALE = 0.125f * 1.4426950408889634f;

    char* wbK = stg[wave];

    bf16x8 qf[4];
    #pragma unroll
    for (int c = 0; c < 4; c++) {
        bf16x8 t = *(const bf16x8*)(Qb + (size_t)qrow * DM + c * 16 + hi * 8);
        #pragma unroll
        for (int jj = 0; jj < 8; jj++) t[jj] = f2bf(bf2f(t[jj]) * QSCALE);
        qf[c] = t;
    }

    f32x16 o0, o1;
    #pragma unroll
    for (int r = 0; r < 16; r++) { o0[r] = 0.f; o1[r] = 0.f; }
    float l_r = 0.f;

    const int i_ = lane;
    const int kcol = (((i_ & 7) ^ (i_ >> 3)) << 3);
    const int krow = (i_ >> 3);
    const short* ksp = Kb + (size_t)(t0 * 32 + krow) * DM + kcol;
    auto stageK = [&]() {
        #pragma unroll
        for (int c = 0; c < 4; c++)
            __builtin_amdgcn_global_load_lds(
                (const __attribute__((address_space(1))) void*)(ksp + (size_t)c * 8 * DM),
                (__attribute__((address_space(3))) void*)(wbK + c * 1024), 16, 0, 0);
        ksp += 32 * DM;
    };

    const short* vsp = Vb + (size_t)t0 * 2048 + (size_t)l31 * 32 + hi * 8;
    bf16x8 kf[4], vf[4];
    auto loadV = [&]() {
        vf[0] = *(const bf16x8*)(vsp);
        vf[1] = *(const bf16x8*)(vsp + 16);
        vf[2] = *(const bf16x8*)(vsp + 1024);
        vf[3] = *(const bf16x8*)(vsp + 1040);
        vsp += 2048;
    };

    const int kx = (l31 & 7) << 4;
    auto readK = [&]() {
        #pragma unroll
        for (int cc = 0; cc < 4; cc++)
            kf[cc] = *(const bf16x8*)(wbK + l31 * 128 + ((cc * 32 + hi * 16) ^ kx));
    };

    if (t0 < t1) {
        stageK();
        loadV();
        asm volatile("s_waitcnt vmcnt(4)" ::: "memory");
        __builtin_amdgcn_sched_barrier(0);
        readK();
    }

    for (int kb = t0; kb < t1; kb++) {
        const int kbase = kb * 32;
        f32x16 st;
        #pragma unroll
        for (int r = 0; r < 16; r++) st[r] = 0.f;
        __builtin_amdgcn_s_setprio(1);
        st = __builtin_amdgcn_mfma_f32_32x32x16_bf16(kf[0], qf[0], st, 0, 0, 0);
        st = __builtin_amdgcn_mfma_f32_32x32x16_bf16(kf[1], qf[1], st, 0, 0, 0);
        st = __builtin_amdgcn_mfma_f32_32x32x16_bf16(kf[2], qf[2], st, 0, 0, 0);
        st = __builtin_amdgcn_mfma_f32_32x32x16_bf16(kf[3], qf[3], st, 0, 0, 0);
        __builtin_amdgcn_s_setprio(0);

        if (kb + 1 < t1) {
            asm volatile("s_waitcnt lgkmcnt(0)" ::: "memory");
            __builtin_amdgcn_sched_barrier(0);
            stageK();
        }

        float p[16];
        if (kb == qt) {
            #pragma unroll
            for (int r = 0; r < 16; r++) {
                int kl = (r & 3) + 8 * (r >> 2) + 4 * hi;
                float v = (kbase + kl > qrow) ? -1e30f : st[r];
                p[r] = EXP2(v);
            }
        } else {
            #pragma unroll
            for (int r = 0; r < 16; r++) p[r] = EXP2(st[r]);
        }

        float s01 = (p[0] + p[1]) + (p[2] + p[3]);
        float s23 = (p[4] + p[5]) + (p[6] + p[7]);
        float s45 = (p[8] + p[9]) + (p[10] + p[11]);
        float s67 = (p[12] + p[13]) + (p[14] + p[15]);
        l_r += (s01 + s23) + (s45 + s67);

        union { uint32_t u[4]; bf16x8 v; } c0, c1;
        #pragma unroll
        for (int i = 0; i < 4; i++) {
            union { float f; uint32_t u; } a0, a1, b0, b1;
            a0.f = p[2 * i];     a1.f = p[2 * i + 1];
            b0.f = p[8 + 2 * i]; b1.f = p[8 + 2 * i + 1];
            c0.u[i] = __builtin_amdgcn_perm(a1.u, a0.u, 0x07060302u);
            c1.u[i] = __builtin_amdgcn_perm(b1.u, b0.u, 0x07060302u);
        }

        __builtin_amdgcn_s_setprio(1);
        o0 = __builtin_amdgcn_mfma_f32_32x32x16_bf16(vf[0], c0.v, o0, 0, 0, 0);
        o0 = __builtin_amdgcn_mfma_f32_32x32x16_bf16(vf[1], c1.v, o0, 0, 0, 0);
        o1 = __builtin_amdgcn_mfma_f32_32x32x16_bf16(vf[2], c0.v, o1, 0, 0, 0);
        o1 = __builtin_amdgcn_mfma_f32_32x32x16_bf16(vf[3], c1.v, o1, 0, 0, 0);
        __builtin_amdgcn_s_setprio(0);

        if (kb + 1 < t1) {
            loadV();
            asm volatile("s_waitcnt vmcnt(4)" ::: "memory");
            __builtin_amdgcn_sched_barrier(0);
            readK();
        }
    }

    l_r += __shfl_xor(l_r, 32);

    const bool publisher = three ? (wave == 1 || wave == 2) : (wave == 1 || wave == 3);
    if (publisher) {
        short* pb = (short*)stg[wave];
        #pragma unroll
        for (int dc = 0; dc < 2; dc++)
            #pragma unroll
            for (int g2 = 0; g2 < 4; g2++) {
                int d = dc * 32 + g2 * 8 + hi * 4;
                s16x4 v4;
                #pragma unroll
                for (int rr = 0; rr < 4; rr++) v4[rr] = f2bf((dc ? o1 : o0)[g2 * 4 + rr]);
                *(s16x4*)(pb + l31 * 68 + d) = v4;
            }
        if (!hi) lLp(wave)[l31] = l_r;
    }
    if (three && wave == 3) {
        float inv = 1.0f / l_r;
        size_t base = ((size_t)b * S_LEN + qrow) * DM + h * DH;
        #pragma unroll
        for (int dc = 0; dc < 2; dc++)
            #pragma unroll
            for (int g2 = 0; g2 < 4; g2++) {
                s16x4 ov;
                #pragma unroll
                for (int rr = 0; rr < 4; rr++)
                    ov[rr] = f2bf((dc ? o1 : o0)[g2 * 4 + rr] * inv);
                *(s16x4*)(Oo + base + dc * 32 + g2 * 8 + hi * 4) = ov;
            }
    }
    __syncthreads();

    const bool merger = three ? (wave == 0) : (wave == 0 || wave == 2);
    if (merger) {
        const short* p1 = (const short*)stg[wave + 1];
        float L = l_r + lLp(wave + 1)[l31];
        const short* p2 = nullptr;
        if (three) { p2 = (const short*)stg[2]; L += lLp(2)[l31]; }
        float inv = 1.0f / L;
        size_t base = ((size_t)b * S_LEN + qrow) * DM + h * DH;
        #pragma unroll
        for (int dc = 0; dc < 2; dc++)
            #pragma unroll
            for (int g2 = 0; g2 < 4; g2++) {
                int d = dc * 32 + g2 * 8 + hi * 4;
                s16x4 a = *(const s16x4*)(p1 + l31 * 68 + d);
                s16x4 ov;
                #pragma unroll
                for (int rr = 0; rr < 4; rr++) {
                    float acc = (dc ? o1 : o0)[g2 * 4 + rr] + bf2f(a[rr]);
                    if (three) acc += bf2f(p2[l31 * 68 + d + rr]);
                    ov[rr] = f2bf(acc * inv);
                }
                *(s16x4*)(Oo + base + d) = ov;
            }
    }
}

extern "C" void kernel_launch(void* const* d_in, const int* in_sizes, int n_in,
                              void* d_out, int out_size, void* d_ws, size_t ws_size,
                              hipStream_t stream) {
    const float* x  = (const float*)d_in[0];
    const float* wq = (const float*)d_in[1];
    const float* wk = (const float*)d_in[2];
    const float* wv = (const float*)d_in[3];
    const float* wo = (const float*)d_in[4];
    float* out = (float*)d_out;

    short* ws = (short*)d_ws;
    size_t off = 0;
    short* xb  = ws + off; off += (size_t)BS * DM;
    short* wqb = ws + off; off += (size_t)DM * DM;   // Wq|Wk|Wv|Wo contiguous
    short* wkb = ws + off; off += (size_t)DM * DM;
    short* wvb = ws + off; off += (size_t)DM * DM;
    short* wob = ws + off; off += (size_t)DM * DM;
    short* Qb  = ws + off; off += (size_t)BS * DM;   // Q|K|Vt contiguous
    short* Kb  = ws + off; off += (size_t)BS * DM;
    short* Vtb = ws + off; off += (size_t)BS * DM;
    short* attn_o = xb;  // reuse: x dead after projections
    (void)wkb; (void)wvb; (void)Kb; (void)Vtb;

    {
        int n4 = (BS * DM) / 4;
        cast_kernel<<<n4 / 256, 256, 0, stream>>>(x, xb, n4);
        int w4 = (DM * DM) / 4;
        cast4_kernel<<<dim3(w4 / 256, 4), 256, 0, stream>>>(wq, wk, wv, wo, wqb, w4);
    }

    // fused QKV projection: 256x128 tile, 512 threads, grid 32x24
    gemm_qkv<<<dim3(BS / 256, (3 * DM) / 128), 512, 0, stream>>>(xb, wqb, Qb);

    attn_stg_kernel<<<dim3(2048), 256, 0, stream>>>(Qb, Qb + (size_t)BS * DM,
                                                    Qb + (size_t)2 * BS * DM, attn_o);

    // output projection: 256x128 tile, 512 threads, grid 32x8
    gemm_out<<<dim3(BS / 256, DM / 128), 512, 0, stream>>>(attn_o, wob, out);
}

// Round 24
// 170.625 us; speedup vs baseline: 1.0264x; 1.0264x over previous
//
#include <hip/hip_runtime.h>
#include <hip/hip_bf16.h>
#include <stdint.h>

// MultiheadSelfAttention B=4 S=2048 D=1024 H=16 dh=64, causal, f32 in/out.
// R24: revert out-projection to R22's 128^2 gemm_bt (R23's 256x128 out-proj
//      at 1 block/CU regressed: too little TLP + 2x write traffic). Keeps
//      R22's gemm_qkv (256x128, 512thr), attn (R16), casts. = best measured.

#define S_LEN 2048
#define DM 1024
#define NH 16
#define NB 4
#define DH 64
#define BS (NB * S_LEN)   // 8192 rows

#if __has_builtin(__builtin_amdgcn_exp2f)
#define EXP2(x) __builtin_amdgcn_exp2f(x)
#else
#define EXP2(x) __expf((x) * 0.6931471805599453f)
#endif

typedef __attribute__((ext_vector_type(4))) float f32x4;
typedef __attribute__((ext_vector_type(16))) float f32x16;
typedef __attribute__((ext_vector_type(8))) short bf16x8;
typedef __attribute__((ext_vector_type(4))) short s16x4;

static __device__ __forceinline__ float bf2f(short u) {
    union { float f; uint32_t i; } c; c.i = ((uint32_t)(uint16_t)u) << 16; return c.f;
}
static __device__ __forceinline__ short f2bf(float f) {
    union { float f; uint32_t i; } c; c.f = f;
    uint32_t r = (c.i + 0x7FFFu + ((c.i >> 16) & 1u)) >> 16;
    return (short)r;
}

// ---------------- casts ----------------
__global__ void cast_kernel(const float* __restrict__ in, short* __restrict__ out, int n4) {
    int i = blockIdx.x * blockDim.x + threadIdx.x;
    if (i >= n4) return;
    f32x4 v = *(const f32x4*)(in + (size_t)i * 4);
    s16x4 o;
    o[0] = f2bf(v[0]); o[1] = f2bf(v[1]); o[2] = f2bf(v[2]); o[3] = f2bf(v[3]);
    *(s16x4*)(out + (size_t)i * 4) = o;
}

__global__ void cast4_kernel(const float* __restrict__ a, const float* __restrict__ b,
                             const float* __restrict__ c, const float* __restrict__ d,
                             short* __restrict__ out, int n4per) {
    int z = blockIdx.y;
    const float* in = z == 0 ? a : z == 1 ? b : z == 2 ? c : d;
    int i = blockIdx.x * blockDim.x + threadIdx.x;
    if (i >= n4per) return;
    f32x4 v = *(const f32x4*)(in + (size_t)i * 4);
    s16x4 o;
    o[0] = f2bf(v[0]); o[1] = f2bf(v[1]); o[2] = f2bf(v[2]); o[3] = f2bf(v[3]);
    *(s16x4*)(out + (size_t)z * n4per * 4 + (size_t)i * 4) = o;
}

// ---------------- fused QKV GEMM, 256x128 tile, 512 threads (R22) ------------
__global__ __launch_bounds__(512) void gemm_qkv(const short* __restrict__ A,
                                                const short* __restrict__ Bm,
                                                short* __restrict__ Outb) {
    __shared__ __align__(16) short lA[2][256 * 32];   // 32KB
    __shared__ __align__(16) short lB[2][128 * 32];   // 16KB
    const int Kd = DM;
    const int tid = threadIdx.x;
    const int lane = tid & 63;
    const int wave = tid >> 6;          // 0..7
    const int wave_m = wave >> 1;       // 0..3
    const int wave_n = wave & 1;        // 0..1
    const int mb = blockIdx.x;
    const int nb = blockIdx.y;
    const int c16 = lane & 15;
    const int g = lane >> 4;

    auto stage = [&](int buf, int kb) {
        #pragma unroll
        for (int i = 0; i < 2; i++) {
            int row = i * 128 + wave * 16 + (lane >> 2);
            int col = (lane & 3) * 8;
            const short* srcA = A + (size_t)(mb * 256 + row) * Kd + kb * 32 + col;
            __builtin_amdgcn_global_load_lds(
                (const __attribute__((address_space(1))) void*)srcA,
                (__attribute__((address_space(3))) void*)(&lA[buf][i * 4096 + wave * 512]),
                16, 0, 0);
        }
        {
            int row = wave * 16 + (lane >> 2);
            int col = (lane & 3) * 8;
            const short* srcB = Bm + (size_t)(nb * 128 + row) * Kd + kb * 32 + col;
            __builtin_amdgcn_global_load_lds(
                (const __attribute__((address_space(1))) void*)srcB,
                (__attribute__((address_space(3))) void*)(&lB[buf][wave * 512]),
                16, 0, 0);
        }
    };

    f32x4 acc[4][4];
    f32x4 zero = {0.f, 0.f, 0.f, 0.f};
    for (int i = 0; i < 4; i++)
        for (int j = 0; j < 4; j++) acc[i][j] = zero;

    const int nk = Kd >> 5;
    stage(0, 0);
    __syncthreads();
    for (int t = 0; t < nk; t++) {
        int cur = t & 1;
        if (t + 1 < nk) stage(cur ^ 1, t + 1);
        bf16x8 af[4], bfr[4];
        for (int i = 0; i < 4; i++) {
            af[i]  = *(const bf16x8*)&lA[cur][(wave_m * 64 + i * 16 + c16) * 32 + g * 8];
            bfr[i] = *(const bf16x8*)&lB[cur][(wave_n * 64 + i * 16 + c16) * 32 + g * 8];
        }
        for (int mi = 0; mi < 4; mi++)
            for (int ni = 0; ni < 4; ni++)
                acc[mi][ni] = __builtin_amdgcn_mfma_f32_16x16x32_bf16(af[mi], bfr[ni], acc[mi][ni], 0, 0, 0);
        __syncthreads();
    }

    const int z = (nb * 128) >> 10;
    short* Cout = Outb + (size_t)z * BS * DM;
    for (int mi = 0; mi < 4; mi++) {
        int row0 = mb * 256 + wave_m * 64 + mi * 16 + g * 4;
        if (z < 2) {
            for (int ni = 0; ni < 4; ni++) {
                int col = (nb * 128 + wave_n * 64 + ni * 16 + c16) & 1023;
                f32x4 a = acc[mi][ni];
                for (int r = 0; r < 4; r++)
                    Cout[(size_t)(row0 + r) * DM + col] = f2bf(a[r]);
            }
        } else {
            int bb = row0 >> 11, s0 = row0 & 2047;
            int kb = s0 >> 5, kl0 = s0 & 31;
            int pos0 = kl0 ^ ((((kl0 >> 2) ^ (kl0 >> 3)) & 1) ? 12 : 0);
            for (int ni = 0; ni < 4; ni++) {
                int col = (nb * 128 + wave_n * 64 + ni * 16 + c16) & 1023;
                int h = col >> 6, d = col & 63;
                f32x4 a = acc[mi][ni];
                s16x4 v4;
                v4[0] = f2bf(a[0]); v4[1] = f2bf(a[1]);
                v4[2] = f2bf(a[2]); v4[3] = f2bf(a[3]);
                *(s16x4*)(Cout + ((((size_t)(bb * NH + h) * 64 + kb) * 64 + d) * 32 + pos0)) = v4;
            }
        }
    }
}

// ---------------- output GEMM: C[M,N] f32 = A[M,K] * B[N,K]^T (128^2, R22) ----
__global__ __launch_bounds__(256) void gemm_bt(const short* __restrict__ A,
                                               const short* __restrict__ Bm,
                                               float* __restrict__ Cout,
                                               int M, int N, int Kd) {
    __shared__ __align__(16) short lA[2][128 * 32];
    __shared__ __align__(16) short lB[2][128 * 32];
    const int tid = threadIdx.x;
    const int lane = tid & 63;
    const int wave = tid >> 6;
    const int mb = blockIdx.x;
    const int nb = blockIdx.y;
    const int wm = (wave >> 1) * 64;
    const int wn = (wave & 1) * 64;
    const int c16 = lane & 15;
    const int g = lane >> 4;

    auto stage = [&](int buf, int kb) {
        for (int i = 0; i < 2; i++) {
            int row = i * 64 + wave * 16 + (lane >> 2);
            int col = (lane & 3) * 8;
            const short* srcA = A + (size_t)(mb * 128 + row) * Kd + kb * 32 + col;
            const short* srcB = Bm + (size_t)(nb * 128 + row) * Kd + kb * 32 + col;
            __builtin_amdgcn_global_load_lds(
                (const __attribute__((address_space(1))) void*)srcA,
                (__attribute__((address_space(3))) void*)(&lA[buf][i * 2048 + wave * 512]),
                16, 0, 0);
            __builtin_amdgcn_global_load_lds(
                (const __attribute__((address_space(1))) void*)srcB,
                (__attribute__((address_space(3))) void*)(&lB[buf][i * 2048 + wave * 512]),
                16, 0, 0);
        }
    };

    f32x4 acc[4][4];
    f32x4 zero = {0.f, 0.f, 0.f, 0.f};
    for (int i = 0; i < 4; i++)
        for (int j = 0; j < 4; j++) acc[i][j] = zero;

    const int nk = Kd >> 5;
    stage(0, 0);
    __syncthreads();
    for (int t = 0; t < nk; t++) {
        int cur = t & 1;
        if (t + 1 < nk) stage(cur ^ 1, t + 1);
        bf16x8 af[4], bfr[4];
        for (int i = 0; i < 4; i++) {
            af[i]  = *(const bf16x8*)&lA[cur][(wm + i * 16 + c16) * 32 + g * 8];
            bfr[i] = *(const bf16x8*)&lB[cur][(wn + i * 16 + c16) * 32 + g * 8];
        }
        for (int mi = 0; mi < 4; mi++)
            for (int ni = 0; ni < 4; ni++)
                acc[mi][ni] = __builtin_amdgcn_mfma_f32_16x16x32_bf16(af[mi], bfr[ni], acc[mi][ni], 0, 0, 0);
        __syncthreads();
    }

    for (int mi = 0; mi < 4; mi++) {
        int row0 = mb * 128 + wm + mi * 16 + g * 4;
        for (int ni = 0; ni < 4; ni++) {
            int col = nb * 128 + wn + ni * 16 + c16;
            f32x4 a = acc[mi][ni];
            for (int r = 0; r < 4; r++)
                Cout[(size_t)(row0 + r) * N + col] = a[r];
        }
    }
}

// ---------------- flash attention (R16 exact): K LDS-staged, V direct ------------
__global__ __launch_bounds__(256, 4) void attn_stg_kernel(const short* __restrict__ Q,
                                                          const short* __restrict__ K,
                                                          const short* __restrict__ Vt,
                                                          short* __restrict__ Oo) {
    __shared__ __align__(16) char stg[4][4608];   // per-wave: K 4KB | partial/lL overlay
    const int lane = threadIdx.x & 63;
    const int wave = threadIdx.x >> 6;
    const int j = blockIdx.x >> 6;        // 0..31
    const int bh = blockIdx.x & 63;       // XCD = bh%8 (round-robin)
    const int b = bh >> 4, h = bh & 15;
    const int l31 = lane & 31;
    const int hi = lane >> 5;
    const bool three = (j <= 20);

    auto lLp = [&](int w) { return (float*)(stg[w] + 4352); };

    const int qtA = 63 - j, qtB = j;
    const int nkA = qtA + 1, nkB = qtB + 1;
    int qt, t0, t1;
    if (three) {
        if (wave < 3) { qt = qtA; t0 = (nkA * wave) / 3; t1 = (nkA * (wave + 1)) / 3; }
        else          { qt = qtB; t0 = 0; t1 = nkB; }
    } else {
        int half = wave & 1;
        if (wave < 2) { int hh = (nkA + 1) >> 1; qt = qtA; t0 = half ? hh : 0; t1 = half ? nkA : hh; }
        else          { int hh = (nkB + 1) >> 1; qt = qtB; t0 = half ? hh : 0; t1 = half ? nkB : hh; }
    }
    const int q0 = qt * 32;
    const int qrow = q0 + l31;

    const short* Qb = Q + (size_t)b * S_LEN * DM + h * DH;
    const short* Kb = K + (size_t)b * S_LEN * DM + h * DH;
    const short* Vb = Vt + (size_t)bh * S_LEN * DH;
    const float QSCALE = 0.125f * 1.4426950408889634f;

    char* wbK = stg[wave];

    bf16x8 qf[4];
    #pragma unroll
    for (int c = 0; c < 4; c++) {
        bf16x8 t = *(const bf16x8*)(Qb + (size_t)qrow * DM + c * 16 + hi * 8);
        #pragma unroll
        for (int jj = 0; jj < 8; jj++) t[jj] = f2bf(bf2f(t[jj]) * QSCALE);
        qf[c] = t;
    }

    f32x16 o0, o1;
    #pragma unroll
    for (int r = 0; r < 16; r++) { o0[r] = 0.f; o1[r] = 0.f; }
    float l_r = 0.f;

    const int i_ = lane;
    const int kcol = (((i_ & 7) ^ (i_ >> 3)) << 3);
    const int krow = (i_ >> 3);
    const short* ksp = Kb + (size_t)(t0 * 32 + krow) * DM + kcol;
    auto stageK = [&]() {
        #pragma unroll
        for (int c = 0; c < 4; c++)
            __builtin_amdgcn_global_load_lds(
                (const __attribute__((address_space(1))) void*)(ksp + (size_t)c * 8 * DM),
                (__attribute__((address_space(3))) void*)(wbK + c * 1024), 16, 0, 0);
        ksp += 32 * DM;
    };

    const short* vsp = Vb + (size_t)t0 * 2048 + (size_t)l31 * 32 + hi * 8;
    bf16x8 kf[4], vf[4];
    auto loadV = [&]() {
        vf[0] = *(const bf16x8*)(vsp);
        vf[1] = *(const bf16x8*)(vsp + 16);
        vf[2] = *(const bf16x8*)(vsp + 1024);
        vf[3] = *(const bf16x8*)(vsp + 1040);
        vsp += 2048;
    };

    const int kx = (l31 & 7) << 4;
    auto readK = [&]() {
        #pragma unroll
        for (int cc = 0; cc < 4; cc++)
            kf[cc] = *(const bf16x8*)(wbK + l31 * 128 + ((cc * 32 + hi * 16) ^ kx));
    };

    if (t0 < t1) {
        stageK();
        loadV();
        asm volatile("s_waitcnt vmcnt(4)" ::: "memory");
        __builtin_amdgcn_sched_barrier(0);
        readK();
    }

    for (int kb = t0; kb < t1; kb++) {
        const int kbase = kb * 32;
        f32x16 st;
        #pragma unroll
        for (int r = 0; r < 16; r++) st[r] = 0.f;
        __builtin_amdgcn_s_setprio(1);
        st = __builtin_amdgcn_mfma_f32_32x32x16_bf16(kf[0], qf[0], st, 0, 0, 0);
        st = __builtin_amdgcn_mfma_f32_32x32x16_bf16(kf[1], qf[1], st, 0, 0, 0);
        st = __builtin_amdgcn_mfma_f32_32x32x16_bf16(kf[2], qf[2], st, 0, 0, 0);
        st = __builtin_amdgcn_mfma_f32_32x32x16_bf16(kf[3], qf[3], st, 0, 0, 0);
        __builtin_amdgcn_s_setprio(0);

        if (kb + 1 < t1) {
            asm volatile("s_waitcnt lgkmcnt(0)" ::: "memory");
            __builtin_amdgcn_sched_barrier(0);
            stageK();
        }

        float p[16];
        if (kb == qt) {
            #pragma unroll
            for (int r = 0; r < 16; r++) {
                int kl = (r & 3) + 8 * (r >> 2) + 4 * hi;
                float v = (kbase + kl > qrow) ? -1e30f : st[r];
                p[r] = EXP2(v);
            }
        } else {
            #pragma unroll
            for (int r = 0; r < 16; r++) p[r] = EXP2(st[r]);
        }

        float s01 = (p[0] + p[1]) + (p[2] + p[3]);
        float s23 = (p[4] + p[5]) + (p[6] + p[7]);
        float s45 = (p[8] + p[9]) + (p[10] + p[11]);
        float s67 = (p[12] + p[13]) + (p[14] + p[15]);
        l_r += (s01 + s23) + (s45 + s67);

        union { uint32_t u[4]; bf16x8 v; } c0, c1;
        #pragma unroll
        for (int i = 0; i < 4; i++) {
            union { float f; uint32_t u; } a0, a1, b0, b1;
            a0.f = p[2 * i];     a1.f = p[2 * i + 1];
            b0.f = p[8 + 2 * i]; b1.f = p[8 + 2 * i + 1];
            c0.u[i] = __builtin_amdgcn_perm(a1.u, a0.u, 0x07060302u);
            c1.u[i] = __builtin_amdgcn_perm(b1.u, b0.u, 0x07060302u);
        }

        __builtin_amdgcn_s_setprio(1);
        o0 = __builtin_amdgcn_mfma_f32_32x32x16_bf16(vf[0], c0.v, o0, 0, 0, 0);
        o0 = __builtin_amdgcn_mfma_f32_32x32x16_bf16(vf[1], c1.v, o0, 0, 0, 0);
        o1 = __builtin_amdgcn_mfma_f32_32x32x16_bf16(vf[2], c0.v, o1, 0, 0, 0);
        o1 = __builtin_amdgcn_mfma_f32_32x32x16_bf16(vf[3], c1.v, o1, 0, 0, 0);
        __builtin_amdgcn_s_setprio(0);

        if (kb + 1 < t1) {
            loadV();
            asm volatile("s_waitcnt vmcnt(4)" ::: "memory");
            __builtin_amdgcn_sched_barrier(0);
            readK();
        }
    }

    l_r += __shfl_xor(l_r, 32);

    const bool publisher = three ? (wave == 1 || wave == 2) : (wave == 1 || wave == 3);
    if (publisher) {
        short* pb = (short*)stg[wave];
        #pragma unroll
        for (int dc = 0; dc < 2; dc++)
            #pragma unroll
            for (int g2 = 0; g2 < 4; g2++) {
                int d = dc * 32 + g2 * 8 + hi * 4;
                s16x4 v4;
                #pragma unroll
                for (int rr = 0; rr < 4; rr++) v4[rr] = f2bf((dc ? o1 : o0)[g2 * 4 + rr]);
                *(s16x4*)(pb + l31 * 68 + d) = v4;
            }
        if (!hi) lLp(wave)[l31] = l_r;
    }
    if (three && wave == 3) {
        float inv = 1.0f / l_r;
        size_t base = ((size_t)b * S_LEN + qrow) * DM + h * DH;
        #pragma unroll
        for (int dc = 0; dc < 2; dc++)
            #pragma unroll
            for (int g2 = 0; g2 < 4; g2++) {
                s16x4 ov;
                #pragma unroll
                for (int rr = 0; rr < 4; rr++)
                    ov[rr] = f2bf((dc ? o1 : o0)[g2 * 4 + rr] * inv);
                *(s16x4*)(Oo + base + dc * 32 + g2 * 8 + hi * 4) = ov;
            }
    }
    __syncthreads();

    const bool merger = three ? (wave == 0) : (wave == 0 || wave == 2);
    if (merger) {
        const short* p1 = (const short*)stg[wave + 1];
        float L = l_r + lLp(wave + 1)[l31];
        const short* p2 = nullptr;
        if (three) { p2 = (const short*)stg[2]; L += lLp(2)[l31]; }
        float inv = 1.0f / L;
        size_t base = ((size_t)b * S_LEN + qrow) * DM + h * DH;
        #pragma unroll
        for (int dc = 0; dc < 2; dc++)
            #pragma unroll
            for (int g2 = 0; g2 < 4; g2++) {
                int d = dc * 32 + g2 * 8 + hi * 4;
                s16x4 a = *(const s16x4*)(p1 + l31 * 68 + d);
                s16x4 ov;
                #pragma unroll
                for (int rr = 0; rr < 4; rr++) {
                    float acc = (dc ? o1 : o0)[g2 * 4 + rr] + bf2f(a[rr]);
                    if (three) acc += bf2f(p2[l31 * 68 + d + rr]);
                    ov[rr] = f2bf(acc * inv);
                }
                *(s16x4*)(Oo + base + d) = ov;
            }
    }
}

extern "C" void kernel_launch(void* const* d_in, const int* in_sizes, int n_in,
                              void* d_out, int out_size, void* d_ws, size_t ws_size,
                              hipStream_t stream) {
    const float* x  = (const float*)d_in[0];
    const float* wq = (const float*)d_in[1];
    const float* wk = (const float*)d_in[2];
    const float* wv = (const float*)d_in[3];
    const float* wo = (const float*)d_in[4];
    float* out = (float*)d_out;

    short* ws = (short*)d_ws;
    size_t off = 0;
    short* xb  = ws + off; off += (size_t)BS * DM;
    short* wqb = ws + off; off += (size_t)DM * DM;   // Wq|Wk|Wv|Wo contiguous
    short* wkb = ws + off; off += (size_t)DM * DM;
    short* wvb = ws + off; off += (size_t)DM * DM;
    short* wob = ws + off; off += (size_t)DM * DM;
    short* Qb  = ws + off; off += (size_t)BS * DM;   // Q|K|Vt contiguous
    short* Kb  = ws + off; off += (size_t)BS * DM;
    short* Vtb = ws + off; off += (size_t)BS * DM;
    short* attn_o = xb;  // reuse: x dead after projections
    (void)wkb; (void)wvb; (void)Kb; (void)Vtb;

    {
        int n4 = (BS * DM) / 4;
        cast_kernel<<<n4 / 256, 256, 0, stream>>>(x, xb, n4);
        int w4 = (DM * DM) / 4;
        cast4_kernel<<<dim3(w4 / 256, 4), 256, 0, stream>>>(wq, wk, wv, wo, wqb, w4);
    }

    // fused QKV projection: 256x128 tile, 512 threads, grid 32x24
    gemm_qkv<<<dim3(BS / 256, (3 * DM) / 128), 512, 0, stream>>>(xb, wqb, Qb);

    attn_stg_kernel<<<dim3(2048), 256, 0, stream>>>(Qb, Qb + (size_t)BS * DM,
                                                    Qb + (size_t)2 * BS * DM, attn_o);

    // output projection: R22's 128^2 structure (512 blocks, 2-3/CU)
    gemm_bt<<<dim3(BS / 128, DM / 128), 256, 0, stream>>>(attn_o, wob, out, BS, DM, DM);
}